// Round 1
// baseline (266302.441 us; speedup 1.0000x reference)
//
#include <hip/hip_runtime.h>
#include <hip/hip_cooperative_groups.h>

namespace cg = cooperative_groups;

#define NN 2048
#define T_TOTAL 16384
#define WASH 200
#define GRID 128
#define BLOCK 256
#define WAVES (BLOCK / 64)                  // 4
#define ROWS_PER_BLOCK (NN / GRID)          // 16
#define ROWS_PER_WAVE (ROWS_PER_BLOCK / WAVES)  // 4
#define COLS_PER_LANE (NN / 64)             // 32

__global__ __launch_bounds__(BLOCK, 1)
void esn_kernel(const float* __restrict__ u,
                const float* __restrict__ w_in,
                const float* __restrict__ w_res,
                const float* __restrict__ w_out,
                const float* __restrict__ w_out_mask,
                float* __restrict__ out,      // d_out: T_TOTAL - WASH floats
                float* __restrict__ xbuf,     // ws: 2*NN floats (double-buffered state)
                float* __restrict__ partial,  // ws: T_TOTAL*GRID floats (may be unused)
                int use_partial)
{
    const int b    = blockIdx.x;
    const int tid  = threadIdx.x;
    const int wave = tid >> 6;
    const int lane = tid & 63;

    // ---- load W into registers: this wave owns rows r0..r0+3, lane holds cols lane+64k ----
    const int r0 = b * ROWS_PER_BLOCK + wave * ROWS_PER_WAVE;
    float wreg[ROWS_PER_WAVE][COLS_PER_LANE];
#pragma unroll
    for (int r = 0; r < ROWS_PER_WAVE; ++r) {
        const float* wrow = w_res + (size_t)(r0 + r) * NN;
#pragma unroll
        for (int k = 0; k < COLS_PER_LANE; ++k)
            wreg[r][k] = wrow[lane + 64 * k];
    }
    float win_r[ROWS_PER_WAVE], c_r[ROWS_PER_WAVE];
#pragma unroll
    for (int r = 0; r < ROWS_PER_WAVE; ++r) {
        win_r[r] = w_in[r0 + r];
        c_r[r]   = w_out[r0 + r] * w_out_mask[r0 + r];
    }

    // ---- zero both x buffers (x0 = 0) ----
    for (int i = b * BLOCK + tid; i < 2 * NN; i += GRID * BLOCK)
        xbuf[i] = 0.0f;

    __shared__ float xs[NN];
    __shared__ float pout[WAVES];

    cg::grid_group grid = cg::this_grid();
    grid.sync();

    for (int t = 0; t < T_TOTAL; ++t) {
        const float* xcur  = xbuf + (t & 1) * NN;
        float*       xnext = xbuf + ((t + 1) & 1) * NN;

        // stage current state into LDS (vectorized, coalesced)
        {
            const float4* xc4 = (const float4*)xcur;
            float4* xs4 = (float4*)xs;
#pragma unroll
            for (int i = 0; i < NN / (4 * BLOCK); ++i)   // 2 float4 per thread
                xs4[tid + i * BLOCK] = xc4[tid + i * BLOCK];
        }
        __syncthreads();

        // per-lane x slice (conflict-free: 64 consecutive lanes -> 64 consecutive banks mod 32, 2-way = free)
        float xv[COLS_PER_LANE];
#pragma unroll
        for (int k = 0; k < COLS_PER_LANE; ++k)
            xv[k] = xs[lane + 64 * k];

        // 4 row dot-products from register-resident W
        float s[ROWS_PER_WAVE];
#pragma unroll
        for (int r = 0; r < ROWS_PER_WAVE; ++r) {
            float acc = 0.0f;
#pragma unroll
            for (int k = 0; k < COLS_PER_LANE; ++k)
                acc = fmaf(wreg[r][k], xv[k], acc);
            s[r] = acc;
        }

        // butterfly reduce each row across the 64-lane wave
#pragma unroll
        for (int r = 0; r < ROWS_PER_WAVE; ++r) {
            float v = s[r];
#pragma unroll
            for (int off = 32; off > 0; off >>= 1)
                v += __shfl_xor(v, off, 64);
            s[r] = v;
        }

        const float ut = u[t];

        // lane 0 of each wave finishes its 4 rows
        if (lane == 0) {
            float p = 0.0f;
#pragma unroll
            for (int r = 0; r < ROWS_PER_WAVE; ++r) {
                float xn = tanhf(fmaf(win_r[r], ut, s[r]));
                xnext[r0 + r] = xn;
                p = fmaf(c_r[r], xn, p);
            }
            pout[wave] = p;
        }
        __syncthreads();

        if (tid == 0) {
            float pb = 0.0f;
#pragma unroll
            for (int wv = 0; wv < WAVES; ++wv) pb += pout[wv];
            if (use_partial) {
                partial[(size_t)t * GRID + b] = pb;
            } else if (t >= WASH) {
                atomicAdd(&out[t - WASH], pb);
            }
        }

        grid.sync();   // xnext fully written & visible -> next step may read it
    }

    // ---- phase 2: deterministic reduction of per-block partials ----
    if (use_partial) {
        for (int t = WASH + b * BLOCK + tid; t < T_TOTAL; t += GRID * BLOCK) {
            const float* pr = partial + (size_t)t * GRID;
            float ssum = 0.0f;
            for (int g = 0; g < GRID; ++g) ssum += pr[g];
            out[t - WASH] = ssum;
        }
    }
}

extern "C" void kernel_launch(void* const* d_in, const int* in_sizes, int n_in,
                              void* d_out, int out_size, void* d_ws, size_t ws_size,
                              hipStream_t stream) {
    const float* u          = (const float*)d_in[0];
    const float* w_in       = (const float*)d_in[1];
    const float* w_res      = (const float*)d_in[2];
    const float* w_out      = (const float*)d_in[3];
    const float* w_out_mask = (const float*)d_in[4];
    float* out = (float*)d_out;

    float* xbuf    = (float*)d_ws;                      // 2*NN floats = 16 KB
    float* partial = (float*)d_ws + 2 * NN;             // T_TOTAL*GRID floats = 8.4 MB
    size_t need = (size_t)(2 * NN + (size_t)T_TOTAL * GRID) * sizeof(float);
    int use_partial = (ws_size >= need) ? 1 : 0;

    // zero output (needed for atomic fallback; harmless otherwise)
    hipMemsetAsync(d_out, 0, (size_t)out_size * sizeof(float), stream);

    void* args[] = {(void*)&u, (void*)&w_in, (void*)&w_res, (void*)&w_out,
                    (void*)&w_out_mask, (void*)&out, (void*)&xbuf,
                    (void*)&partial, (void*)&use_partial};
    hipLaunchCooperativeKernel((void*)esn_kernel, dim3(GRID), dim3(BLOCK),
                               args, 0, stream);
}

// Round 3
// 114767.920 us; speedup vs baseline: 2.3204x; 2.3204x over previous
//
#include <hip/hip_runtime.h>
#include <hip/hip_cooperative_groups.h>

namespace cg = cooperative_groups;

#define NN 2048
#define T_TOTAL 16384
#define WASH 200
#define GRID 128
#define BLOCK 256
#define WAVES (BLOCK / 64)                      // 4
#define ROWS_PER_BLOCK (NN / GRID)              // 16
#define ROWS_PER_WAVE (ROWS_PER_BLOCK / WAVES)  // 4
#define COLS_PER_LANE (NN / 64)                 // 32
#define NGRP 8
#define BLKS_PER_GRP (GRID / NGRP)              // 16
#define CNT_STRIDE 16                           // one 64B line per counter
#define CNT_WORDS ((NGRP + 1) * CNT_STRIDE)     // 144

__global__ __launch_bounds__(BLOCK, 1)
void esn_kernel(const float* __restrict__ u,
                const float* __restrict__ w_in,
                const float* __restrict__ w_res,
                const float* __restrict__ w_out,
                const float* __restrict__ w_out_mask,
                float* __restrict__ out,       // d_out: T_TOTAL - WASH floats
                float* __restrict__ xbuf,      // ws: 2*NN floats (double-buffered state)
                unsigned* __restrict__ cnts,   // ws: CNT_WORDS uints (barrier counters)
                float* __restrict__ partial,   // ws: T_TOTAL*GRID floats
                int use_partial)
{
    const int b    = blockIdx.x;
    const int tid  = threadIdx.x;
    const int wave = tid >> 6;
    const int lane = tid & 63;

    // ---- W into registers: wave owns rows r0..r0+3, lane holds cols lane+64k ----
    const int r0 = b * ROWS_PER_BLOCK + wave * ROWS_PER_WAVE;
    float wreg[ROWS_PER_WAVE][COLS_PER_LANE];
#pragma unroll
    for (int r = 0; r < ROWS_PER_WAVE; ++r) {
        const float* wrow = w_res + (size_t)(r0 + r) * NN;
#pragma unroll
        for (int k = 0; k < COLS_PER_LANE; ++k)
            wreg[r][k] = wrow[lane + 64 * k];
    }
    float win_r[ROWS_PER_WAVE], c_r[ROWS_PER_WAVE];
#pragma unroll
    for (int r = 0; r < ROWS_PER_WAVE; ++r) {
        win_r[r] = w_in[r0 + r];
        c_r[r]   = w_out[r0 + r] * w_out_mask[r0 + r];
    }

    // ---- init: x0 = 0 and barrier counters = 0, published via agent-scope stores ----
    for (int i = b * BLOCK + tid; i < 2 * NN; i += GRID * BLOCK)
        __hip_atomic_store(&xbuf[i], 0.0f, __ATOMIC_RELAXED, __HIP_MEMORY_SCOPE_AGENT);
    if (b == 0 && tid < CNT_WORDS)
        __hip_atomic_store(&cnts[tid], 0u, __ATOMIC_RELAXED, __HIP_MEMORY_SCOPE_AGENT);

    __shared__ float xs[NN];
    __shared__ float pout[WAVES];

    cg::this_grid().sync();   // once; sanctioned full-fence publication of init

    unsigned* grp_cnt  = &cnts[0];
    unsigned* root_cnt = &cnts[NGRP * CNT_STRIDE];

    for (int t = 0; t < T_TOTAL; ++t) {
        const float* xcur  = xbuf + (t & 1) * NN;
        float*       xnext = xbuf + ((t + 1) & 1) * NN;

        // stage current state into LDS — plain vectorized loads are safe: the
        // previous step's acquire fence (buffer_inv) invalidated L1/L2, and the
        // writers stored through to the MALL.
        {
            const float4* xc4 = (const float4*)xcur;
            float4* xs4 = (float4*)xs;
#pragma unroll
            for (int i = 0; i < NN / (4 * BLOCK); ++i)   // 2 float4 per thread
                xs4[tid + i * BLOCK] = xc4[tid + i * BLOCK];
        }
        const float ut = u[t];   // issued early; consumed after the dot products
        __syncthreads();

        // per-lane x slice
        float xv[COLS_PER_LANE];
#pragma unroll
        for (int k = 0; k < COLS_PER_LANE; ++k)
            xv[k] = xs[lane + 64 * k];

        // 4 row dot-products from register-resident W
        float s[ROWS_PER_WAVE];
#pragma unroll
        for (int r = 0; r < ROWS_PER_WAVE; ++r) {
            float acc = 0.0f;
#pragma unroll
            for (int k = 0; k < COLS_PER_LANE; ++k)
                acc = fmaf(wreg[r][k], xv[k], acc);
            s[r] = acc;
        }

        // butterfly reduce each row across the wave
#pragma unroll
        for (int r = 0; r < ROWS_PER_WAVE; ++r) {
            float v = s[r];
#pragma unroll
            for (int off = 32; off > 0; off >>= 1)
                v += __shfl_xor(v, off, 64);
            s[r] = v;
        }

        // lane 0 of each wave finishes its rows; x stores go through to the MALL
        if (lane == 0) {
            float p = 0.0f;
#pragma unroll
            for (int r = 0; r < ROWS_PER_WAVE; ++r) {
                float xn = tanhf(fmaf(win_r[r], ut, s[r]));
                __hip_atomic_store(&xnext[r0 + r], xn,
                                   __ATOMIC_RELAXED, __HIP_MEMORY_SCOPE_AGENT);
                p = fmaf(c_r[r], xn, p);
            }
            pout[wave] = p;
        }

        // drains vmcnt in every wave -> all 16 x-stores of this block are at the
        // coherence point before thread 0 arrives at the barrier
        __syncthreads();

        if (tid == 0) {
            float pb = pout[0] + pout[1] + pout[2] + pout[3];
            if (use_partial) {
                __hip_atomic_store(&partial[(size_t)t * GRID + b], pb,
                                   __ATOMIC_RELAXED, __HIP_MEMORY_SCOPE_AGENT);
            } else if (t >= WASH) {
                atomicAdd(&out[t - WASH], pb);
            }
            asm volatile("s_waitcnt vmcnt(0)" ::: "memory");  // drain partial store

            // two-level arrive: 8 group counters, last arriver bumps root
            unsigned old = __hip_atomic_fetch_add(&grp_cnt[(b & (NGRP - 1)) * CNT_STRIDE],
                                                  1u, __ATOMIC_RELAXED,
                                                  __HIP_MEMORY_SCOPE_AGENT);
            if ((old % BLKS_PER_GRP) == (BLKS_PER_GRP - 1))
                __hip_atomic_fetch_add(root_cnt, 1u, __ATOMIC_RELAXED,
                                       __HIP_MEMORY_SCOPE_AGENT);

            const unsigned tgt = (unsigned)(t + 1) * NGRP;
            while (__hip_atomic_load(root_cnt, __ATOMIC_RELAXED,
                                     __HIP_MEMORY_SCOPE_AGENT) < tgt) { }
        }

        // one buffer_inv per step: subsequent plain loads see fresh MALL data
        __builtin_amdgcn_fence(__ATOMIC_ACQUIRE, "agent");
        __syncthreads();
    }

    // ---- phase 2: deterministic reduction of per-block partials ----
    if (use_partial) {
        for (int t = WASH + b * BLOCK + tid; t < T_TOTAL; t += GRID * BLOCK) {
            const float* pr = partial + (size_t)t * GRID;
            float ssum = 0.0f;
            for (int g = 0; g < GRID; ++g) ssum += pr[g];
            out[t - WASH] = ssum;
        }
    }
}

extern "C" void kernel_launch(void* const* d_in, const int* in_sizes, int n_in,
                              void* d_out, int out_size, void* d_ws, size_t ws_size,
                              hipStream_t stream) {
    const float* u          = (const float*)d_in[0];
    const float* w_in       = (const float*)d_in[1];
    const float* w_res      = (const float*)d_in[2];
    const float* w_out      = (const float*)d_in[3];
    const float* w_out_mask = (const float*)d_in[4];
    float* out = (float*)d_out;

    float*    xbuf    = (float*)d_ws;                                  // 2*NN floats
    unsigned* cnts    = (unsigned*)((float*)d_ws + 2 * NN);            // CNT_WORDS uints
    float*    partial = (float*)d_ws + 2 * NN + CNT_WORDS;             // T*GRID floats
    size_t need = (size_t)(2 * NN + CNT_WORDS + (size_t)T_TOTAL * GRID) * sizeof(float);
    int use_partial = (ws_size >= need) ? 1 : 0;

    // zero output (needed for atomic fallback; harmless otherwise)
    (void)hipMemsetAsync(d_out, 0, (size_t)out_size * sizeof(float), stream);

    void* args[] = {(void*)&u, (void*)&w_in, (void*)&w_res, (void*)&w_out,
                    (void*)&w_out_mask, (void*)&out, (void*)&xbuf,
                    (void*)&cnts, (void*)&partial, (void*)&use_partial};
    (void)hipLaunchCooperativeKernel((void*)esn_kernel, dim3(GRID), dim3(BLOCK),
                                     args, 0, stream);
}

// Round 4
// 64174.518 us; speedup vs baseline: 4.1497x; 1.7884x over previous
//
#include <hip/hip_runtime.h>
#include <hip/hip_cooperative_groups.h>

namespace cg = cooperative_groups;

typedef unsigned long long u64;

#define NN 2048
#define T_TOTAL 16384
#define WASH 200
#define GRID 128
#define BLOCK 256
#define WAVES (BLOCK / 64)                      // 4
#define ROWS_PER_BLOCK (NN / GRID)              // 16
#define ROWS_PER_WAVE (ROWS_PER_BLOCK / WAVES)  // 4
#define COLS_PER_LANE (NN / 64)                 // 32
#define PPT (NN / BLOCK)                        // 8 pairs per thread

// state element: high 32 = float bits of x, low 32 = step tag.
// Written as ONE relaxed agent-scope 8B atomic store -> tag and value are
// inseparable; readers poll until tag matches, then the value is valid.
// Skew proof: a block enters step t only after seeing ALL tags == t, which
// implies every block finished step t-1 and thus consumed buffer (t-1)&1.
// The next write into a buffer holding tag t is tag t+2, issued from step
// t+1, which requires all tags t+1 present -> everyone is done reading
// tag-t data. Two buffers suffice; no barrier, no fence, no RMW.

__global__ __launch_bounds__(BLOCK, 1)
void esn_kernel(const float* __restrict__ u,
                const float* __restrict__ w_in,
                const float* __restrict__ w_res,
                const float* __restrict__ w_out,
                const float* __restrict__ w_out_mask,
                float* __restrict__ out,       // d_out: T_TOTAL - WASH floats
                u64* __restrict__ pairs,       // ws: 2*NN tagged state (dbuf)
                float* __restrict__ partial,   // ws: T_TOTAL*GRID floats
                int use_partial)
{
    const int b    = blockIdx.x;
    const int tid  = threadIdx.x;
    const int wave = tid >> 6;
    const int lane = tid & 63;
    const int r0   = b * ROWS_PER_BLOCK + wave * ROWS_PER_WAVE;

    // ---- W into registers: wave owns 4 rows, lane holds cols lane+64k ----
    float wreg[ROWS_PER_WAVE][COLS_PER_LANE];
#pragma unroll
    for (int r = 0; r < ROWS_PER_WAVE; ++r) {
        const float* wrow = w_res + (size_t)(r0 + r) * NN;
#pragma unroll
        for (int k = 0; k < COLS_PER_LANE; ++k)
            wreg[r][k] = wrow[lane + 64 * k];
    }
    float win_r[ROWS_PER_WAVE], c_r[ROWS_PER_WAVE];
#pragma unroll
    for (int r = 0; r < ROWS_PER_WAVE; ++r) {
        win_r[r] = w_in[r0 + r];
        c_r[r]   = w_out[r0 + r] * w_out_mask[r0 + r];
    }

    // ---- publish x_0 = 0 tagged step 0 (own rows only; self-synchronizing).
    // Stale tags from a previous replay are 16384/16383, never 0 -> ABA-safe.
    if (tid < ROWS_PER_BLOCK)
        __hip_atomic_store(&pairs[b * ROWS_PER_BLOCK + tid], 0ull,
                           __ATOMIC_RELAXED, __HIP_MEMORY_SCOPE_AGENT);

    __shared__ float xs[2][NN];       // double-buffered -> 1 syncthreads/step
    __shared__ float pout[2][WAVES];  // double-buffered wave output partials

    for (int t = 0; t < T_TOTAL; ++t) {
        u64* __restrict__ bcur  = pairs + (size_t)(t & 1) * NN;
        u64* __restrict__ bnext = pairs + (size_t)((t + 1) & 1) * NN;
        const unsigned tag = (unsigned)t;

        // ---- poll-gather: 8 coalesced 8B atomic loads per thread ----
        u64 v[PPT];
        for (;;) {
#pragma unroll
            for (int j = 0; j < PPT; ++j)
                v[j] = __hip_atomic_load(&bcur[tid + BLOCK * j],
                                         __ATOMIC_RELAXED,
                                         __HIP_MEMORY_SCOPE_AGENT);
            bool ok = true;
#pragma unroll
            for (int j = 0; j < PPT; ++j)
                ok &= ((unsigned)v[j] == tag);
            if (ok) break;
        }
#pragma unroll
        for (int j = 0; j < PPT; ++j)
            xs[t & 1][tid + BLOCK * j] = __uint_as_float((unsigned)(v[j] >> 32));

        const float ut = u[t];
        __syncthreads();   // the ONLY block barrier per step

        // deferred output partial for step t-1 (pout[(t-1)&1] is stable:
        // concurrent writers this step target pout[t&1])
        if (tid == 0 && t > 0) {
            const float* pp = pout[(t - 1) & 1];
            float pb = pp[0] + pp[1] + pp[2] + pp[3];
            if (use_partial) partial[(size_t)(t - 1) * GRID + b] = pb;
            else if (t - 1 >= WASH) atomicAdd(&out[t - 1 - WASH], pb);
        }

        // per-lane x slice
        float xv[COLS_PER_LANE];
#pragma unroll
        for (int k = 0; k < COLS_PER_LANE; ++k)
            xv[k] = xs[t & 1][lane + 64 * k];

        // 4 row dot-products from register-resident W
        float s[ROWS_PER_WAVE];
#pragma unroll
        for (int r = 0; r < ROWS_PER_WAVE; ++r) {
            float acc = 0.0f;
#pragma unroll
            for (int k = 0; k < COLS_PER_LANE; ++k)
                acc = fmaf(wreg[r][k], xv[k], acc);
            s[r] = acc;
        }
#pragma unroll
        for (int r = 0; r < ROWS_PER_WAVE; ++r) {
#pragma unroll
            for (int off = 32; off > 0; off >>= 1)
                s[r] += __shfl_xor(s[r], off, 64);
        }

        // lane 0 finishes rows: tanh, publish tagged pair (fire-and-forget)
        if (lane == 0) {
            float p = 0.0f;
#pragma unroll
            for (int r = 0; r < ROWS_PER_WAVE; ++r) {
                float xn = tanhf(fmaf(win_r[r], ut, s[r]));
                u64 pk = ((u64)__float_as_uint(xn) << 32) | (u64)(tag + 1u);
                __hip_atomic_store(&bnext[r0 + r], pk,
                                   __ATOMIC_RELAXED, __HIP_MEMORY_SCOPE_AGENT);
                p = fmaf(c_r[r], xn, p);
            }
            pout[t & 1][wave] = p;
        }
    }

    // tail: flush output partial for the last step
    __syncthreads();
    if (tid == 0) {
        const float* pp = pout[(T_TOTAL - 1) & 1];
        float pb = pp[0] + pp[1] + pp[2] + pp[3];
        if (use_partial) partial[(size_t)(T_TOTAL - 1) * GRID + b] = pb;
        else atomicAdd(&out[T_TOTAL - 1 - WASH], pb);
    }

    cg::this_grid().sync();   // once; fences partial[] for phase 2

    // ---- phase 2: deterministic reduction of per-block partials ----
    if (use_partial) {
        for (int t = WASH + b * BLOCK + tid; t < T_TOTAL; t += GRID * BLOCK) {
            const float* pr = partial + (size_t)t * GRID;
            float ssum = 0.0f;
            for (int g = 0; g < GRID; ++g) ssum += pr[g];
            out[t - WASH] = ssum;
        }
    }
}

extern "C" void kernel_launch(void* const* d_in, const int* in_sizes, int n_in,
                              void* d_out, int out_size, void* d_ws, size_t ws_size,
                              hipStream_t stream) {
    const float* u          = (const float*)d_in[0];
    const float* w_in       = (const float*)d_in[1];
    const float* w_res      = (const float*)d_in[2];
    const float* w_out      = (const float*)d_in[3];
    const float* w_out_mask = (const float*)d_in[4];
    float* out = (float*)d_out;

    u64*   pairs   = (u64*)d_ws;                          // 2*NN u64 = 32 KB
    float* partial = (float*)((u64*)d_ws + 2 * NN);       // T_TOTAL*GRID floats
    size_t need = 2 * NN * sizeof(u64) + (size_t)T_TOTAL * GRID * sizeof(float);
    int use_partial = (ws_size >= need) ? 1 : 0;

    // zero output (needed for atomic fallback; harmless otherwise)
    (void)hipMemsetAsync(d_out, 0, (size_t)out_size * sizeof(float), stream);

    void* args[] = {(void*)&u, (void*)&w_in, (void*)&w_res, (void*)&w_out,
                    (void*)&w_out_mask, (void*)&out, (void*)&pairs,
                    (void*)&partial, (void*)&use_partial};
    (void)hipLaunchCooperativeKernel((void*)esn_kernel, dim3(GRID), dim3(BLOCK),
                                     args, 0, stream);
}

// Round 5
// 45475.885 us; speedup vs baseline: 5.8559x; 1.4112x over previous
//
#include <hip/hip_runtime.h>
#include <hip/hip_cooperative_groups.h>

namespace cg = cooperative_groups;
typedef unsigned long long u64;

#define NN 2048
#define T_TOTAL 16384
#define WASH 200
#define GRID 128
#define BLOCK 512
#define WAVES (BLOCK / 64)                      // 8
#define ROWS_PER_BLOCK (NN / GRID)              // 16
#define ROWS_PER_WAVE (ROWS_PER_BLOCK / WAVES)  // 2
#define COLS_PER_LANE (NN / 64)                 // 32
#define U64_PER_THREAD (NN / 2 / BLOCK)         // 2
#define SENT_STRIDE 16                          // one 64B line per sentinel

// Sync protocol (per-block sentinel, double-buffered):
//  - producer block b, iteration t: stores its 16 x_{t+1} floats (4B agent
//    atomics, write-through to MALL), drains vmcnt (barrier C), then tid0
//    stores sent[(t+1)&1][b] = t+1. Sentinel visible => the 16 values are
//    already at the coherence point (vmcnt ack precedes sentinel issue).
//  - consumer, iteration t: wave 0 polls all 128 sentinels of slot [t&1]
//    for == t (monotone, equality-safe: slot can't advance to t+2 until
//    this block itself publishes t+1). Barrier A gates the whole block,
//    then ONE value sweep (agent atomic loads) reads fresh MALL data.
//  - skew bound 1 step => 2 buffers suffice; stale tags from a previous
//    replay (16384/16383/0xAAAAAAAA) never equal the polled step. No
//    fences, no RMW, no grid.sync in the loop.

__device__ __forceinline__ float fast_tanh(float x) {
    // tanh(x) = 1 - 2/(e^{2x}+1);  e^{2x} = exp2(x * 2/ln2)
    float e = exp2f(x * 2.88539008177792681f);   // v_exp_f32 path
    return 1.0f - 2.0f / (e + 1.0f);             // inf-> +1, 0 -> -1 : correct
}

__global__ __launch_bounds__(BLOCK, 1)
void esn_kernel(const float* __restrict__ u,
                const float* __restrict__ w_in,
                const float* __restrict__ w_res,
                const float* __restrict__ w_out,
                const float* __restrict__ w_out_mask,
                float* __restrict__ out,       // d_out: T_TOTAL - WASH floats
                float* __restrict__ vbuf,      // ws: 2*NN floats (state dbuf)
                unsigned* __restrict__ sent,   // ws: 2*GRID*SENT_STRIDE u32
                float* __restrict__ partial,   // ws: T_TOTAL*GRID floats
                int use_partial)
{
    const int b    = blockIdx.x;
    const int tid  = threadIdx.x;
    const int wave = tid >> 6;
    const int lane = tid & 63;
    const int r0   = b * ROWS_PER_BLOCK + wave * ROWS_PER_WAVE;

    // ---- W into registers: wave owns 2 rows, lane holds cols lane+64k ----
    float wreg[ROWS_PER_WAVE][COLS_PER_LANE];
#pragma unroll
    for (int r = 0; r < ROWS_PER_WAVE; ++r) {
        const float* wrow = w_res + (size_t)(r0 + r) * NN;
#pragma unroll
        for (int k = 0; k < COLS_PER_LANE; ++k)
            wreg[r][k] = wrow[lane + 64 * k];
    }
    // per-lane row constants (meaningful for lane < ROWS_PER_WAVE)
    const int   myr   = lane & (ROWS_PER_WAVE - 1);
    const float win_m = w_in[r0 + myr];
    const float c_m   = w_out[r0 + myr] * w_out_mask[r0 + myr];

    // ---- init: publish x_0 = 0 for own rows, drain, then sentinel 0 ----
    if (tid < ROWS_PER_BLOCK)
        __hip_atomic_store(&vbuf[b * ROWS_PER_BLOCK + tid], 0.0f,
                           __ATOMIC_RELAXED, __HIP_MEMORY_SCOPE_AGENT);
    asm volatile("s_waitcnt vmcnt(0)" ::: "memory");
    __syncthreads();
    if (tid == 0)
        __hip_atomic_store(&sent[b * SENT_STRIDE], 0u,
                           __ATOMIC_RELAXED, __HIP_MEMORY_SCOPE_AGENT);

    __shared__ float xs[NN];
    __shared__ float pout[ROWS_PER_BLOCK];

    for (int t = 0; t < T_TOTAL; ++t) {
        const u64* __restrict__ vcur  = (const u64*)(vbuf + (size_t)(t & 1) * NN);
        float*     __restrict__ vnext = vbuf + (size_t)((t + 1) & 1) * NN;
        unsigned*  __restrict__ scur  = sent + (size_t)(t & 1) * GRID * SENT_STRIDE;
        unsigned*  __restrict__ snext = sent + (size_t)((t + 1) & 1) * GRID * SENT_STRIDE;
        const unsigned tg = (unsigned)t;

        // ---- detect: wave 0 polls the 128 per-block sentinels (2 per lane) ----
        if (wave == 0) {
            unsigned* p0 = &scur[lane * SENT_STRIDE];
            unsigned* p1 = &scur[(lane + 64) * SENT_STRIDE];
            while (__hip_atomic_load(p0, __ATOMIC_RELAXED,
                                     __HIP_MEMORY_SCOPE_AGENT) != tg) { }
            while (__hip_atomic_load(p1, __ATOMIC_RELAXED,
                                     __HIP_MEMORY_SCOPE_AGENT) != tg) { }
        }
        const float ut = u[t];
        __syncthreads();   // A: all sentinels == t observed -> values valid

        // ---- single value sweep: 2 coalesced 8B atomic loads per thread ----
        u64 d[U64_PER_THREAD];
#pragma unroll
        for (int j = 0; j < U64_PER_THREAD; ++j)
            d[j] = __hip_atomic_load(&vcur[tid + BLOCK * j],
                                     __ATOMIC_RELAXED, __HIP_MEMORY_SCOPE_AGENT);
#pragma unroll
        for (int j = 0; j < U64_PER_THREAD; ++j) {
            xs[2 * (tid + BLOCK * j)]     = __uint_as_float((unsigned)d[j]);
            xs[2 * (tid + BLOCK * j) + 1] = __uint_as_float((unsigned)(d[j] >> 32));
        }
        __syncthreads();   // B: xs staged

        // deferred: tid0 flushes the PREVIOUS step's output partial
        if (tid == 0 && t > 0) {
            float pb = 0.0f;
#pragma unroll
            for (int i = 0; i < ROWS_PER_BLOCK; ++i) pb += pout[i];
            if (use_partial) partial[(size_t)(t - 1) * GRID + b] = pb;
            else if (t - 1 >= WASH) atomicAdd(&out[t - 1 - WASH], pb);
        }

        // ---- per-lane x slice + 2 row dot-products from register W ----
        float xv[COLS_PER_LANE];
#pragma unroll
        for (int k = 0; k < COLS_PER_LANE; ++k)
            xv[k] = xs[lane + 64 * k];

        float s[ROWS_PER_WAVE];
#pragma unroll
        for (int r = 0; r < ROWS_PER_WAVE; ++r) {
            float acc = 0.0f;
#pragma unroll
            for (int k = 0; k < COLS_PER_LANE; ++k)
                acc = fmaf(wreg[r][k], xv[k], acc);
            s[r] = acc;
        }
#pragma unroll
        for (int r = 0; r < ROWS_PER_WAVE; ++r) {
#pragma unroll
            for (int off = 32; off > 0; off >>= 1)
                s[r] += __shfl_xor(s[r], off, 64);
        }

        // ---- parallel finish: lanes 0..ROWS_PER_WAVE-1 each own one row ----
        if (lane < ROWS_PER_WAVE) {
            float sm = (lane == 0) ? s[0] : s[1];
            float xn = fast_tanh(fmaf(win_m, ut, sm));
            __hip_atomic_store(&vnext[r0 + myr], xn,
                               __ATOMIC_RELAXED, __HIP_MEMORY_SCOPE_AGENT);
            pout[wave * ROWS_PER_WAVE + myr] = c_m * xn;
        }

        asm volatile("s_waitcnt vmcnt(0)" ::: "memory");
        __syncthreads();   // C: all 16 value stores ack'd at coherence point

        if (tid == 0)
            __hip_atomic_store(&snext[b * SENT_STRIDE], tg + 1u,
                               __ATOMIC_RELAXED, __HIP_MEMORY_SCOPE_AGENT);
    }

    // tail: flush output partial for the last step
    if (tid == 0) {
        float pb = 0.0f;
#pragma unroll
        for (int i = 0; i < ROWS_PER_BLOCK; ++i) pb += pout[i];
        if (use_partial) partial[(size_t)(T_TOTAL - 1) * GRID + b] = pb;
        else atomicAdd(&out[T_TOTAL - 1 - WASH], pb);
    }

    cg::this_grid().sync();   // once; publishes partial[] for phase 2

    // ---- phase 2: deterministic reduction of per-block partials ----
    if (use_partial) {
        for (int t = WASH + b * BLOCK + tid; t < T_TOTAL; t += GRID * BLOCK) {
            const float* pr = partial + (size_t)t * GRID;
            float ssum = 0.0f;
            for (int g = 0; g < GRID; ++g) ssum += pr[g];
            out[t - WASH] = ssum;
        }
    }
}

extern "C" void kernel_launch(void* const* d_in, const int* in_sizes, int n_in,
                              void* d_out, int out_size, void* d_ws, size_t ws_size,
                              hipStream_t stream) {
    const float* u          = (const float*)d_in[0];
    const float* w_in       = (const float*)d_in[1];
    const float* w_res      = (const float*)d_in[2];
    const float* w_out      = (const float*)d_in[3];
    const float* w_out_mask = (const float*)d_in[4];
    float* out = (float*)d_out;

    float*    vbuf    = (float*)d_ws;                               // 16 KB
    unsigned* sent    = (unsigned*)(vbuf + 2 * NN);                 // 16 KB
    float*    partial = (float*)(sent + 2 * GRID * SENT_STRIDE);    // 8 MB
    size_t need = (size_t)(2 * NN + 2 * GRID * SENT_STRIDE
                           + (size_t)T_TOTAL * GRID) * 4;
    int use_partial = (ws_size >= need) ? 1 : 0;

    // zero output (needed for atomic fallback; harmless otherwise)
    (void)hipMemsetAsync(d_out, 0, (size_t)out_size * sizeof(float), stream);

    void* args[] = {(void*)&u, (void*)&w_in, (void*)&w_res, (void*)&w_out,
                    (void*)&w_out_mask, (void*)&out, (void*)&vbuf,
                    (void*)&sent, (void*)&partial, (void*)&use_partial};
    (void)hipLaunchCooperativeKernel((void*)esn_kernel, dim3(GRID), dim3(BLOCK),
                                     args, 0, stream);
}